// Round 13
// baseline (28.771 us; speedup 1.0000x reference)
//
#include <hip/hip_runtime.h>
#include <math.h>

#define N_PIX 8192      // 2*64*64
#define D 64
#define HW 4096         // h*w
#define BSTRIDE 262144  // d*h*w
#define C1 14.4269504088896340736f   // 10 * log2(e); |dot| <= 1
#define NSEG 32
#define SEGCOLS (N_PIX / NSEG)       // 256 cols per col-segment
#define BC SEGCOLS                   // whole segment staged once (32KB LDS)

typedef __attribute__((ext_vector_type(8))) short short8;   // 8 bf16 = 4 VGPR
typedef __attribute__((ext_vector_type(4))) float f32x4;

#define LDS_AS __attribute__((address_space(3)))
#define GLB_AS __attribute__((address_space(1)))

__device__ inline ushort f2bf(float x) {   // fp32 -> bf16 RNE
    uint u = __float_as_uint(x);
    return (ushort)((u + 0x7FFFu + ((u >> 16) & 1u)) >> 16);
}
__device__ inline float bflo(uint u) { return __uint_as_float(u << 16); }
__device__ inline float bfhi(uint u) { return __uint_as_float(u & 0xFFFF0000u); }

// async 16B global->LDS (dest = wave-uniform base + lane*16)
__device__ inline void gll16(const ushort* g, ushort* l) {
    __builtin_amdgcn_global_load_lds((const GLB_AS uint*)g, (LDS_AS uint*)l, 16, 0, 0);
}

// Stage BC cols x 64 ch bf16 (BC*128B) into ldsbuf, XOR-swizzled.
// LDS[row][slot16] = G[row][slot16 ^ (row&7)]; read undoes the XOR. Verified r8-r12.
__device__ inline void stage(const ushort* __restrict__ z2b, int jcol,
                             ushort* ldsbuf, int wave, int lane) {
    int l3 = lane >> 3, l7 = lane & 7;
    int xo = (l7 ^ l3) << 3;     // ushort offset of swizzled 16B slot
#pragma unroll
    for (int q = 0; q < BC / 32; ++q) {
        int c = wave * (BC / 32) + q;
        const ushort* src = z2b + (size_t)(jcol + c * 8 + l3) * D + xo;
        gll16(src, ldsbuf + c * 512);
    }
}

// ---------- K1: transpose + L2-normalize -> bf16 rows (N,64); 4 threads/pixel ----------
__global__ __launch_bounds__(256) void knorm(const float* __restrict__ z1,
                                             const float* __restrict__ z2,
                                             ushort* __restrict__ z1b,
                                             ushort* __restrict__ z2b,
                                             float* __restrict__ out) {
    int gid = blockIdx.x * 256 + threadIdx.x;   // 0..65535
    if (gid == 0) out[0] = 0.f;                 // fold memset (knorm precedes kfinal)
    int q = gid & 3;                             // channel quarter
    int pixg = gid >> 2;                         // 0..16383
    int t = pixg >> 13;
    int n = pixg & (N_PIX - 1);
    const float* src = t ? z2 : z1;
    ushort* dst = t ? z2b : z1b;
    int b = n >> 12;
    int p = n & 4095;
    const float* base = src + b * BSTRIDE + (q * 16) * HW + p;
    float v[16];
    float ss = 0.f;
#pragma unroll
    for (int c = 0; c < 16; ++c) { v[c] = base[c * HW]; ss += v[c] * v[c]; }
    ss += __shfl_xor(ss, 1);                     // 4-lane group shares pixel
    ss += __shfl_xor(ss, 2);
    float inv = 1.0f / fmaxf(sqrtf(ss), 1e-12f);
    uint4 w0, w1;
#pragma unroll
    for (int c2 = 0; c2 < 8; ++c2) {
        uint val = (uint)f2bf(v[2 * c2] * inv) | ((uint)f2bf(v[2 * c2 + 1] * inv) << 16);
        if (c2 < 4) ((uint*)&w0)[c2] = val; else ((uint*)&w1)[c2 - 4] = val;
    }
    uint4* o = (uint4*)(dst + (size_t)n * D + q * 16);
    o[0] = w0;
    o[1] = w1;
}

// ---------- K2: MFMA sim + fixed-shift exp; single-stage, ZERO mid barriers ----------
// block = 4 waves x 32 rows = 128 rows x 256 cols; grid (64, 32) = 2048 blocks.
// __launch_bounds__(256,4): guarantee 4 blocks/CU (16 waves), cap 128 VGPR.
__global__ __launch_bounds__(256, 4) void ksim(const ushort* __restrict__ z1b,
                                               const ushort* __restrict__ z2b,
                                               float* __restrict__ ps) {
    __shared__ ushort lds[BC * D];   // 32KB
    int tid = threadIdx.x;
    int wave = tid >> 6, lane = tid & 63;
    int lrow = lane & 15;        // A-row / B-col within 16
    int lk = lane >> 4;          // k-chunk 0..3
    int rbase = blockIdx.x * 128 + wave * 32;
    int jbase = blockIdx.y * SEGCOLS;

    stage(z2b, jbase, lds, wave, lane);          // 8 async 1KB chunks per wave

    // A fragments: 2 row-tiles x 2 k-halves (fixed all kernel)
    const ushort* ar = z1b + (size_t)(rbase + lrow) * D + lk * 8;
    short8 a00 = *(const short8*)ar;
    short8 a01 = *(const short8*)(ar + 32);
    short8 a10 = *(const short8*)(ar + 16 * D);
    short8 a11 = *(const short8*)(ar + 16 * D + 32);

    // dual accumulator banks (even/odd ct) break the serial add chain
    float s0a[4] = {0.f, 0.f, 0.f, 0.f}, s0b[4] = {0.f, 0.f, 0.f, 0.f};
    float s1a[4] = {0.f, 0.f, 0.f, 0.f}, s1b[4] = {0.f, 0.f, 0.f, 0.f};

    __syncthreads();                             // drain staging, once

    const char* bb = (const char*)lds;
    int sw = (lrow & 7);
    f32x4 z = {0.f, 0.f, 0.f, 0.f};

#define CT_BODY(CT, S0, S1)                                                        \
    {                                                                              \
        int rowoff = ((CT) * 16 + lrow) << 7;                                      \
        short8 blo = *(const short8*)(bb + rowoff + ((lk ^ sw) << 4));             \
        short8 bhi = *(const short8*)(bb + rowoff + (((4 + lk) ^ sw) << 4));       \
        f32x4 acc0 = __builtin_amdgcn_mfma_f32_16x16x32_bf16(a00, blo, z, 0, 0, 0);\
        f32x4 acc1 = __builtin_amdgcn_mfma_f32_16x16x32_bf16(a10, blo, z, 0, 0, 0);\
        acc0 = __builtin_amdgcn_mfma_f32_16x16x32_bf16(a01, bhi, acc0, 0, 0, 0);   \
        acc1 = __builtin_amdgcn_mfma_f32_16x16x32_bf16(a11, bhi, acc1, 0, 0, 0);   \
        _Pragma("unroll")                                                          \
        for (int r = 0; r < 4; ++r) {                                              \
            S0[r] += __builtin_amdgcn_exp2f(fmaf(acc0[r], C1, -C1));               \
            S1[r] += __builtin_amdgcn_exp2f(fmaf(acc1[r], C1, -C1));               \
        }                                                                          \
    }

#pragma unroll
    for (int ct2 = 0; ct2 < BC / 32; ++ct2) {
        CT_BODY(2 * ct2, s0a, s1a)
        CT_BODY(2 * ct2 + 1, s0b, s1b)
    }
#undef CT_BODY

    float s0[4], s1[4];
#pragma unroll
    for (int r = 0; r < 4; ++r) { s0[r] = s0a[r] + s0b[r]; s1[r] = s1a[r] + s1b[r]; }

    // reduce over 16 lanes sharing lk (different cols, same rows)
#pragma unroll
    for (int off = 1; off <= 8; off <<= 1) {
#pragma unroll
        for (int r = 0; r < 4; ++r) {
            s0[r] += __shfl_xor(s0[r], off);
            s1[r] += __shfl_xor(s1[r], off);
        }
    }
    if (lrow == 0) {
        int seg = blockIdx.y;
        int r0 = rbase + lk * 4;
#pragma unroll
        for (int r = 0; r < 4; ++r) {
            ps[(size_t)(r0 + r) * NSEG + seg] = s0[r];
            ps[(size_t)(r0 + 16 + r) * NSEG + seg] = s1[r];
        }
    }
}

// ---------- K3 (fused final): combine partials + diag + mean via atomic ----------
__global__ __launch_bounds__(256) void kfinal(const ushort* __restrict__ z1b,
                                              const ushort* __restrict__ z2b,
                                              const float* __restrict__ ps,
                                              float* __restrict__ out) {
    __shared__ float wsum[4];
    int tid = threadIdx.x;
    int row = blockIdx.x * 256 + tid;

    const f32x4* pp = (const f32x4*)(ps + (size_t)row * NSEG);
    float s = 0.f;
#pragma unroll
    for (int q = 0; q < NSEG / 4; ++q) {
        f32x4 v = pp[q];
        s += (v[0] + v[1]) + (v[2] + v[3]);
    }
    const uint4* xp = (const uint4*)(z1b + (size_t)row * D);
    const uint4* yp = (const uint4*)(z2b + (size_t)row * D);
    float d = 0.f;
#pragma unroll
    for (int q = 0; q < 8; ++q) {
        uint4 x = xp[q], y = yp[q];
        d = fmaf(bflo(x.x), bflo(y.x), d); d = fmaf(bfhi(x.x), bfhi(y.x), d);
        d = fmaf(bflo(x.y), bflo(y.y), d); d = fmaf(bfhi(x.y), bfhi(y.y), d);
        d = fmaf(bflo(x.z), bflo(y.z), d); d = fmaf(bfhi(x.z), bfhi(y.z), d);
        d = fmaf(bflo(x.w), bflo(y.w), d); d = fmaf(bfhi(x.w), bfhi(y.w), d);
    }
    float val = 10.0f + __logf(s) - 10.0f * d;

#pragma unroll
    for (int off = 32; off > 0; off >>= 1) val += __shfl_down(val, off);
    if ((tid & 63) == 0) wsum[tid >> 6] = val;
    __syncthreads();
    if (tid == 0) {
        float t = (wsum[0] + wsum[1]) + (wsum[2] + wsum[3]);
        atomicAdd(out, t * (1.0f / (float)N_PIX));
    }
}

extern "C" void kernel_launch(void* const* d_in, const int* in_sizes, int n_in,
                              void* d_out, int out_size, void* d_ws, size_t ws_size,
                              hipStream_t stream) {
    const float* z1 = (const float*)d_in[0];
    const float* z2 = (const float*)d_in[1];
    float* out = (float*)d_out;

    ushort* z1b = (ushort*)d_ws;                        // 1 MB
    ushort* z2b = z1b + (size_t)N_PIX * D;              // 1 MB
    float* ps   = (float*)(z2b + (size_t)N_PIX * D);    // 8192*32*4 = 1 MB

    knorm<<<256, 256, 0, stream>>>(z1, z2, z1b, z2b, out);
    dim3 g2(N_PIX / 128, NSEG);                         // (64, 32) = 2048 blocks
    ksim<<<g2, 256, 0, stream>>>(z1b, z2b, ps);
    kfinal<<<N_PIX / 256, 256, 0, stream>>>(z1b, z2b, ps, out);
}

// Round 14
// 27.758 us; speedup vs baseline: 1.0365x; 1.0365x over previous
//
#include <hip/hip_runtime.h>
#include <math.h>

#define N_PIX 8192      // 2*64*64
#define D 64
#define HW 4096         // h*w
#define BSTRIDE 262144  // d*h*w
#define C1 14.4269504088896340736f   // 10 * log2(e); |dot| <= 1
#define NSEG 32
#define SEGCOLS (N_PIX / NSEG)       // 256 cols per col-segment
#define BC SEGCOLS                   // whole segment staged once (32KB LDS)

typedef __attribute__((ext_vector_type(8))) short short8;   // 8 bf16 = 4 VGPR
typedef __attribute__((ext_vector_type(4))) float f32x4;

#define LDS_AS __attribute__((address_space(3)))
#define GLB_AS __attribute__((address_space(1)))

__device__ inline ushort f2bf(float x) {   // fp32 -> bf16 RNE
    uint u = __float_as_uint(x);
    return (ushort)((u + 0x7FFFu + ((u >> 16) & 1u)) >> 16);
}
__device__ inline float bflo(uint u) { return __uint_as_float(u << 16); }
__device__ inline float bfhi(uint u) { return __uint_as_float(u & 0xFFFF0000u); }

// async 16B global->LDS (dest = wave-uniform base + lane*16)
__device__ inline void gll16(const ushort* g, ushort* l) {
    __builtin_amdgcn_global_load_lds((const GLB_AS uint*)g, (LDS_AS uint*)l, 16, 0, 0);
}

// Stage BC cols x 64 ch bf16 (BC*128B) into ldsbuf, XOR-swizzled.
// LDS[row][slot16] = G[row][slot16 ^ (row&7)]; read undoes the XOR. Verified r8-r13.
__device__ inline void stage(const ushort* __restrict__ z2b, int jcol,
                             ushort* ldsbuf, int wave, int lane) {
    int l3 = lane >> 3, l7 = lane & 7;
    int xo = (l7 ^ l3) << 3;     // ushort offset of swizzled 16B slot
#pragma unroll
    for (int q = 0; q < BC / 32; ++q) {
        int c = wave * (BC / 32) + q;
        const ushort* src = z2b + (size_t)(jcol + c * 8 + l3) * D + xo;
        gll16(src, ldsbuf + c * 512);
    }
}

// ---------- K1: transpose + L2-normalize -> bf16 rows (N,64); 4 threads/pixel ----------
__global__ __launch_bounds__(256) void knorm(const float* __restrict__ z1,
                                             const float* __restrict__ z2,
                                             ushort* __restrict__ z1b,
                                             ushort* __restrict__ z2b,
                                             float* __restrict__ out) {
    int gid = blockIdx.x * 256 + threadIdx.x;   // 0..65535
    if (gid == 0) out[0] = 0.f;                 // fold memset (knorm precedes kfinal)
    int q = gid & 3;                             // channel quarter
    int pixg = gid >> 2;                         // 0..16383
    int t = pixg >> 13;
    int n = pixg & (N_PIX - 1);
    const float* src = t ? z2 : z1;
    ushort* dst = t ? z2b : z1b;
    int b = n >> 12;
    int p = n & 4095;
    const float* base = src + b * BSTRIDE + (q * 16) * HW + p;
    float v[16];
    float ss = 0.f;
#pragma unroll
    for (int c = 0; c < 16; ++c) { v[c] = base[c * HW]; ss += v[c] * v[c]; }
    ss += __shfl_xor(ss, 1);                     // 4-lane group shares pixel
    ss += __shfl_xor(ss, 2);
    float inv = 1.0f / fmaxf(sqrtf(ss), 1e-12f);
    uint4 w0, w1;
#pragma unroll
    for (int c2 = 0; c2 < 8; ++c2) {
        uint val = (uint)f2bf(v[2 * c2] * inv) | ((uint)f2bf(v[2 * c2 + 1] * inv) << 16);
        if (c2 < 4) ((uint*)&w0)[c2] = val; else ((uint*)&w1)[c2 - 4] = val;
    }
    uint4* o = (uint4*)(dst + (size_t)n * D + q * 16);
    o[0] = w0;
    o[1] = w1;
}

// ---------- K2: MFMA sim + fixed-shift exp; 64 rows/wave, zero mid barriers ----------
// block = 4 waves x 64 rows = 256 rows x 256 cols; grid (32, 32) = 1024 blocks
// = exactly 4 blocks/CU x 256 CU, one resident generation.
// Per ct: 2 ds_read feed 8 MFMA (4 row-tiles) -> LDS-read traffic halved vs r13.
__global__ __launch_bounds__(256, 4) void ksim(const ushort* __restrict__ z1b,
                                               const ushort* __restrict__ z2b,
                                               float* __restrict__ ps) {
    __shared__ ushort lds[BC * D];   // 32KB
    int tid = threadIdx.x;
    int wave = tid >> 6, lane = tid & 63;
    int lrow = lane & 15;        // A-row / B-col within 16
    int lk = lane >> 4;          // k-chunk 0..3
    int rbase = blockIdx.x * 256 + wave * 64;
    int jbase = blockIdx.y * SEGCOLS;

    stage(z2b, jbase, lds, wave, lane);          // 8 async 1KB chunks per wave

    // A fragments: 4 row-tiles x 2 k-halves
    const ushort* ar = z1b + (size_t)(rbase + lrow) * D + lk * 8;
    short8 a0[4], a1[4];
#pragma unroll
    for (int rt = 0; rt < 4; ++rt) {
        a0[rt] = *(const short8*)(ar + rt * 16 * D);
        a1[rt] = *(const short8*)(ar + rt * 16 * D + 32);
    }

    float s[16];
#pragma unroll
    for (int i = 0; i < 16; ++i) s[i] = 0.f;

    __syncthreads();                             // drain staging, once

    const char* bb = (const char*)lds;
    int sw = (lrow & 7);
    f32x4 z = {0.f, 0.f, 0.f, 0.f};

#pragma unroll
    for (int ct = 0; ct < BC / 16; ++ct) {
        int rowoff = (ct * 16 + lrow) << 7;
        short8 blo = *(const short8*)(bb + rowoff + ((lk ^ sw) << 4));
        short8 bhi = *(const short8*)(bb + rowoff + (((4 + lk) ^ sw) << 4));
#pragma unroll
        for (int rt = 0; rt < 4; ++rt) {
            f32x4 acc = __builtin_amdgcn_mfma_f32_16x16x32_bf16(a0[rt], blo, z, 0, 0, 0);
            acc = __builtin_amdgcn_mfma_f32_16x16x32_bf16(a1[rt], bhi, acc, 0, 0, 0);
#pragma unroll
            for (int r = 0; r < 4; ++r)
                s[rt * 4 + r] += __builtin_amdgcn_exp2f(fmaf(acc[r], C1, -C1));
        }
    }

    // reduce over 16 lanes sharing lk (different cols, same rows)
#pragma unroll
    for (int off = 1; off <= 8; off <<= 1) {
#pragma unroll
        for (int i = 0; i < 16; ++i) s[i] += __shfl_xor(s[i], off);
    }
    if (lrow == 0) {
        int seg = blockIdx.y;
#pragma unroll
        for (int rt = 0; rt < 4; ++rt)
#pragma unroll
            for (int r = 0; r < 4; ++r)
                ps[(size_t)(rbase + rt * 16 + lk * 4 + r) * NSEG + seg] = s[rt * 4 + r];
    }
}

// ---------- K3 (fused final): combine partials + diag + mean via atomic ----------
// 128 blocks x 64 threads (1 wave each) -> spread over half the CUs.
__global__ __launch_bounds__(64) void kfinal(const ushort* __restrict__ z1b,
                                             const ushort* __restrict__ z2b,
                                             const float* __restrict__ ps,
                                             float* __restrict__ out) {
    int tid = threadIdx.x;
    int row = blockIdx.x * 64 + tid;

    const f32x4* pp = (const f32x4*)(ps + (size_t)row * NSEG);
    float s = 0.f;
#pragma unroll
    for (int q = 0; q < NSEG / 4; ++q) {
        f32x4 v = pp[q];
        s += (v[0] + v[1]) + (v[2] + v[3]);
    }
    const uint4* xp = (const uint4*)(z1b + (size_t)row * D);
    const uint4* yp = (const uint4*)(z2b + (size_t)row * D);
    float d = 0.f;
#pragma unroll
    for (int q = 0; q < 8; ++q) {
        uint4 x = xp[q], y = yp[q];
        d = fmaf(bflo(x.x), bflo(y.x), d); d = fmaf(bfhi(x.x), bfhi(y.x), d);
        d = fmaf(bflo(x.y), bflo(y.y), d); d = fmaf(bfhi(x.y), bfhi(y.y), d);
        d = fmaf(bflo(x.z), bflo(y.z), d); d = fmaf(bfhi(x.z), bfhi(y.z), d);
        d = fmaf(bflo(x.w), bflo(y.w), d); d = fmaf(bfhi(x.w), bfhi(y.w), d);
    }
    float val = 10.0f + __logf(s) - 10.0f * d;

#pragma unroll
    for (int off = 32; off > 0; off >>= 1) val += __shfl_down(val, off);
    if (tid == 0) atomicAdd(out, val * (1.0f / (float)N_PIX));
}

extern "C" void kernel_launch(void* const* d_in, const int* in_sizes, int n_in,
                              void* d_out, int out_size, void* d_ws, size_t ws_size,
                              hipStream_t stream) {
    const float* z1 = (const float*)d_in[0];
    const float* z2 = (const float*)d_in[1];
    float* out = (float*)d_out;

    ushort* z1b = (ushort*)d_ws;                        // 1 MB
    ushort* z2b = z1b + (size_t)N_PIX * D;              // 1 MB
    float* ps   = (float*)(z2b + (size_t)N_PIX * D);    // 8192*32*4 = 1 MB

    knorm<<<256, 256, 0, stream>>>(z1, z2, z1b, z2b, out);
    dim3 g2(N_PIX / 256, NSEG);                         // (32, 32) = 1024 blocks
    ksim<<<g2, 256, 0, stream>>>(z1b, z2b, ps);
    kfinal<<<N_PIX / 64, 64, 0, stream>>>(z1b, z2b, ps, out);
}